// Round 3
// baseline (617.783 us; speedup 1.0000x reference)
//
#include <hip/hip_runtime.h>
#include <stdint.h>

#define B_     128
#define T_     64
#define HW_    2048
#define N_     131072
#define NB_    16384      /* N_/8 bytes of src bitmask per row */
#define BINS1  8192
#define SHIFT1 19
#define MARGIN 512u
#define CAP    40960      /* band candidates per row (tgt ~27.5k expected) */
#define NB2A   8448       /* resolveE sub-bins = 33*256, covers 2^19+2*512 ulps @64/bin */
#define SUBCAP 1024
#define HGRID  (B_ * 16)  /* histA: 16 segs/row, 4 t-slots (8192 elems) per block */
#define FULLG  (B_ * 64)  /* maskD: 64 slots/row, 2048 elems per block */

// ---------- helpers ----------

__device__ __forceinline__ uint32_t fkey(float p) {
  uint32_t u = __float_as_uint(p);
  return u ^ ((u & 0x80000000u) ? 0xFFFFFFFFu : 0x80000000u);
}

// fast natural log: hardware v_log_f32 (log2) * ln2; drift vs exact <= ~32 key-ulps here.
__device__ __forceinline__ float fastln(float x) {
  #pragma clang fp contract(off)
  float l2 = __log2f(x);
  return l2 * 0.6931471805599453f;
}

// exact: correctly-rounded f32 natural log via double (matches numpy f32 log on these inputs — R2 verified)
__device__ __forceinline__ float exactln(float x) {
  return (float)log((double)x);
}

// ---------- LUT: per (b,t) constants, exact f32 semantics ----------
__global__ void lut_kernel(const float* __restrict__ Uts, const float* __restrict__ Utt,
                           float* c1src, float* c1tgt, float* cpref) {
  #pragma clang fp contract(off)
  int b = blockIdx.x, t = threadIdx.x;
  c1src[b * T_ + t] = exactln(Uts[b * T_ + t]) * 0.5f;
  c1tgt[b * T_ + t] = exactln(Utt[b * T_ + t]) * 0.5f;
  if (b == 0) {
    const double st = (0.001 - 1.0) / 63.0;   // numpy linspace step (f64)
    double a = (double)t * st;
    double y = a + 1.0;
    if (t == 63) y = 0.001;                   // numpy endpoint fixup
    float L = (float)y;
    float ex = (float)(1.0 / 3.0);
    float pf = (float)pow((double)L, (double)ex);
    if (pf < 1e-9f) pf = 1e-9f;
    cpref[t] = exactln(pf);
    if (t == 0) cpref[64] = exactln(1e-9f);
  }
}

// ---------- A: 13-bit histogram of fast keys, 8192 elems/block ----------
template <bool TGT>
__global__ __launch_bounds__(256) void histA(const float* __restrict__ U0,
                                             const float* __restrict__ c1lut,
                                             const float* __restrict__ cpref,
                                             const uint8_t* __restrict__ bits,
                                             uint32_t* __restrict__ hist1) {
  #pragma clang fp contract(off)
  __shared__ uint32_t lh[BINS1];
  for (int i = threadIdx.x; i < BINS1; i += 256) lh[i] = 0;
  __syncthreads();
  int row = blockIdx.x >> 4, seg = blockIdx.x & 15;
  const float* rowp = U0 + (size_t)row * N_;
  float u[32];
  uint8_t byteg[4];
  #pragma unroll
  for (int g = 0; g < 4; g++) {   // issue all 8 float4 loads up front (MLP)
    int slot = seg * 4 + g;
    int n0 = slot * HW_ + threadIdx.x * 8;
    const float4* p = (const float4*)(rowp + n0);
    float4 va = p[0], vb = p[1];
    u[g*8+0]=va.x; u[g*8+1]=va.y; u[g*8+2]=va.z; u[g*8+3]=va.w;
    u[g*8+4]=vb.x; u[g*8+5]=vb.y; u[g*8+6]=vb.z; u[g*8+7]=vb.w;
    byteg[g] = TGT ? bits[(size_t)row * NB_ + (n0 >> 3)] : (uint8_t)0;
  }
  float lc9 = cpref[64];
  #pragma unroll
  for (int g = 0; g < 4; g++) {
    int slot = seg * 4 + g;
    float c1 = c1lut[row * T_ + slot];
    float c2s = cpref[slot];
    #pragma unroll
    for (int j = 0; j < 8; j++) {
      float c2 = TGT ? ((((byteg[g] >> j) & 1) != 0) ? lc9 : 0.0f) : c2s;
      float P = (fastln(u[g*8+j]) + c1) + c2;
      atomicAdd(&lh[fkey(P) >> SHIFT1], 1u);
    }
  }
  __syncthreads();
  uint32_t* gh = hist1 + (size_t)row * BINS1;
  for (int i = threadIdx.x; i < BINS1; i += 256)
    if (lh[i]) atomicAdd(&gh[i], lh[i]);
}

// ---------- pick bin1 (descending rank K) -> lo1 ----------
__global__ void pickbin1(const uint32_t* __restrict__ hist1, const int* __restrict__ pK,
                         uint32_t* lo1) {
  __shared__ uint32_t sh[256];
  int row = blockIdx.x;
  const uint32_t* h = hist1 + (size_t)row * BINS1;
  const int CH = BINS1 / 256;
  uint32_t s = 0;
  int c0 = threadIdx.x * CH;
  for (int i = 0; i < CH; i++) s += h[c0 + i];
  sh[threadIdx.x] = s;
  __syncthreads();
  if (threadIdx.x == 0) {
    uint32_t K = (uint32_t)*pK;
    uint32_t cum = 0, bin = 0;
    for (int c = 255; c >= 0; c--) {
      if (cum + sh[c] >= K) {
        uint32_t cc = cum;
        for (int b0 = c * CH + CH - 1; b0 >= c * CH; b0--) {
          uint32_t hv = h[b0];
          if (cc + hv >= K) { bin = (uint32_t)b0; break; }
          cc += hv;
        }
        break;
      }
      cum += sh[c];
    }
    lo1[row] = bin << SHIFT1;
  }
}

// ---------- D: write mask (int32 0/1), block-aggregated band gather, count above ----------
template <bool TGT>
__global__ __launch_bounds__(256) void maskD(const float* __restrict__ U0,
                                             const float* __restrict__ c1lut,
                                             const float* __restrict__ cpref,
                                             const uint8_t* __restrict__ bits_in,
                                             const uint32_t* __restrict__ lo1v,
                                             int* __restrict__ out,
                                             uint8_t* __restrict__ bits_out,
                                             uint32_t* __restrict__ bandcnt,
                                             uint32_t* __restrict__ cntabove,
                                             uint32_t* __restrict__ bandidx) {
  #pragma clang fp contract(off)
  __shared__ uint32_t lbase, labove, gbase;
  if (threadIdx.x == 0) { lbase = 0; labove = 0; }
  __syncthreads();
  int row = blockIdx.x >> 6, slot = blockIdx.x & 63;
  int n0 = slot * HW_ + threadIdx.x * 8;
  uint32_t lo1 = lo1v[row];
  uint32_t blo = (lo1 >= MARGIN) ? lo1 - MARGIN : 0u;
  uint32_t bhi = lo1 + ((1u << SHIFT1) - 1u);
  uint32_t bhi2 = bhi + MARGIN;
  bhi = (bhi2 < bhi) ? 0xFFFFFFFFu : bhi2;   // saturate
  const float4* p = (const float4*)(U0 + (size_t)row * N_ + n0);
  float4 va = p[0], vb = p[1];
  float u[8] = {va.x, va.y, va.z, va.w, vb.x, vb.y, vb.z, vb.w};
  float c1 = c1lut[row * T_ + slot];
  float c2s = cpref[slot];
  float lc9 = cpref[64];
  uint8_t byte = TGT ? bits_in[(size_t)row * NB_ + (n0 >> 3)] : (uint8_t)0;
  int ov[8];
  uint32_t bandmask = 0, abovemask = 0;
  #pragma unroll
  for (int j = 0; j < 8; j++) {
    float c2 = TGT ? ((((byte >> j) & 1) != 0) ? lc9 : 0.0f) : c2s;
    float P = (fastln(u[j]) + c1) + c2;
    uint32_t k = fkey(P);
    if (k > bhi) { ov[j] = 1; abovemask |= (1u << j); }
    else { ov[j] = 0; if (k >= blo) bandmask |= (1u << j); }
  }
  int4 o0 = {ov[0], ov[1], ov[2], ov[3]};
  int4 o1 = {ov[4], ov[5], ov[6], ov[7]};
  int4* q = (int4*)(out + (size_t)row * N_ + n0);
  q[0] = o0; q[1] = o1;
  if (!TGT) bits_out[(size_t)row * NB_ + (n0 >> 3)] = (uint8_t)abovemask;
  int bp = __popc(bandmask), ap = __popc(abovemask);
  uint32_t mybase = 0;
  if (bp) mybase = atomicAdd(&lbase, (uint32_t)bp);
  if (ap) atomicAdd(&labove, (uint32_t)ap);
  __syncthreads();
  if (threadIdx.x == 0) {
    gbase = lbase ? atomicAdd(&bandcnt[row], lbase) : 0u;
    if (labove) atomicAdd(&cntabove[row], labove);
  }
  __syncthreads();
  if (bp) {
    uint32_t base = gbase + mybase;
    uint32_t* br = bandidx + (size_t)row * CAP;
    #pragma unroll
    for (int j = 0; j < 8; j++)
      if ((bandmask >> j) & 1u) {
        uint32_t pos = base + (uint32_t)__popc(bandmask & ((1u << j) - 1u));
        if (pos < CAP) br[pos] = (uint32_t)(n0 + j);
      }
  }
}

// ---------- E: exact resolve of the band: sub-hist on exact keys + tiny pairwise ----------
template <bool TGT>
__global__ __launch_bounds__(256) void resolveE(const float* __restrict__ U0,
                                                const float* __restrict__ c1lut,
                                                const float* __restrict__ cpref,
                                                const uint8_t* __restrict__ bits_in,
                                                const int* __restrict__ pK,
                                                const uint32_t* __restrict__ lo1v,
                                                const uint32_t* __restrict__ bandcnt,
                                                const uint32_t* __restrict__ cntabove,
                                                const uint32_t* __restrict__ bandidx,
                                                int* __restrict__ out,
                                                uint8_t* __restrict__ bits_out) {
  #pragma clang fp contract(off)
  __shared__ uint32_t subh[NB2A];
  __shared__ uint32_t sh[256];
  __shared__ uint32_t subk[SUBCAP];
  __shared__ uint32_t subi[SUBCAP];
  __shared__ uint32_t s_bin, s_ca2, s_nsub;
  int row = blockIdx.x;
  for (int i = threadIdx.x; i < NB2A; i += 256) subh[i] = 0;
  if (threadIdx.x == 0) s_nsub = 0;
  __syncthreads();
  uint32_t cnt = bandcnt[row]; if (cnt > CAP) cnt = CAP;
  uint32_t K = (uint32_t)*pK;
  uint32_t R = K - cntabove[row];           // >=1 by construction
  long long base = (long long)lo1v[row] - (long long)MARGIN;
  const float* rowp = U0 + (size_t)row * N_;
  const uint8_t* rb = bits_in + (size_t)row * NB_;
  const uint32_t* bidx = bandidx + (size_t)row * CAP;
  float lc9 = cpref[64];

  // pass 1: exact keys -> sub-histogram (4-wide for gather ILP)
  for (uint32_t b0 = 0; b0 < cnt; b0 += 1024) {
    uint32_t i0 = b0 + threadIdx.x * 4;
    uint32_t idxv[4]; float uvv[4];
    #pragma unroll
    for (int j = 0; j < 4; j++) if (i0 + j < cnt) idxv[j] = bidx[i0 + j];
    #pragma unroll
    for (int j = 0; j < 4; j++) if (i0 + j < cnt) uvv[j] = rowp[idxv[j]];
    #pragma unroll
    for (int j = 0; j < 4; j++) if (i0 + j < cnt) {
      uint32_t idx = idxv[j];
      uint32_t t = idx >> 11;
      float c2 = TGT ? ((((rb[idx >> 3] >> (idx & 7)) & 1) != 0) ? lc9 : 0.0f) : cpref[t];
      float P = (exactln(uvv[j]) + c1lut[row * T_ + t]) + c2;
      long long off = (long long)fkey(P) - base;
      int bin = (int)(off >> 6);
      bin = bin < 0 ? 0 : (bin >= NB2A ? NB2A - 1 : bin);
      atomicAdd(&subh[bin], 1u);
    }
  }
  __syncthreads();
  // pick sub-bin s (descending rank R), count above it
  const int CH2 = NB2A / 256;   // 33
  {
    uint32_t s = 0;
    int c0 = threadIdx.x * CH2;
    for (int i = 0; i < CH2; i++) s += subh[c0 + i];
    sh[threadIdx.x] = s;
  }
  __syncthreads();
  if (threadIdx.x == 0) {
    uint32_t cum = 0, ca2 = 0; int sbin = 0;
    for (int c = 255; c >= 0; c--) {
      if (cum + sh[c] >= R) {
        uint32_t cc = cum;
        for (int b0 = c * CH2 + CH2 - 1; b0 >= c * CH2; b0--) {
          uint32_t hv = subh[b0];
          if (cc + hv >= R) { sbin = b0; ca2 = cc; break; }
          cc += hv;
        }
        break;
      }
      cum += sh[c];
    }
    s_bin = (uint32_t)sbin; s_ca2 = ca2;
  }
  __syncthreads();
  int sbin = (int)s_bin;
  uint32_t R2 = R - s_ca2;
  int* orow = out + (size_t)row * N_;

  // pass 2: recompute exact keys, decide bins>s, collect bin==s
  for (uint32_t b0 = 0; b0 < cnt; b0 += 1024) {
    uint32_t i0 = b0 + threadIdx.x * 4;
    uint32_t idxv[4]; float uvv[4];
    #pragma unroll
    for (int j = 0; j < 4; j++) if (i0 + j < cnt) idxv[j] = bidx[i0 + j];
    #pragma unroll
    for (int j = 0; j < 4; j++) if (i0 + j < cnt) uvv[j] = rowp[idxv[j]];
    #pragma unroll
    for (int j = 0; j < 4; j++) if (i0 + j < cnt) {
      uint32_t idx = idxv[j];
      uint32_t t = idx >> 11;
      float c2 = TGT ? ((((rb[idx >> 3] >> (idx & 7)) & 1) != 0) ? lc9 : 0.0f) : cpref[t];
      float P = (exactln(uvv[j]) + c1lut[row * T_ + t]) + c2;
      uint32_t ek = fkey(P);
      long long off = (long long)ek - base;
      int bin = (int)(off >> 6);
      bin = bin < 0 ? 0 : (bin >= NB2A ? NB2A - 1 : bin);
      if (bin > sbin) {
        orow[idx] = 1;
        if (!TGT) atomicOr((uint32_t*)(bits_out + (size_t)row * NB_) + (idx >> 5), 1u << (idx & 31));
      } else if (bin == sbin) {
        uint32_t ppos = atomicAdd(&s_nsub, 1u);
        if (ppos < SUBCAP) { subk[ppos] = ek; subi[ppos] = idx; }
      }
    }
  }
  __syncthreads();
  uint32_t nsub = s_nsub; if (nsub > SUBCAP) nsub = SUBCAP;
  // pass 3: stable pairwise rank inside sub-bin s, take top R2
  for (uint32_t i = threadIdx.x; i < nsub; i += 256) {
    uint32_t k = subk[i], id = subi[i], r = 0;
    for (uint32_t j = 0; j < nsub; j++) {
      uint32_t kj = subk[j];
      r += (uint32_t)((kj > k) || (kj == k && subi[j] < id));
    }
    if (r < R2) {
      orow[id] = 1;
      if (!TGT) atomicOr((uint32_t*)(bits_out + (size_t)row * NB_) + (id >> 5), 1u << (id & 31));
    }
  }
}

// ---------- launch ----------
extern "C" void kernel_launch(void* const* d_in, const int* in_sizes, int n_in,
                              void* d_out, int out_size, void* d_ws, size_t ws_size,
                              hipStream_t stream) {
  const float* U0s = (const float*)d_in[0];
  const float* Uts = (const float*)d_in[1];
  const float* U0t = (const float*)d_in[2];
  const float* Utt = (const float*)d_in[3];
  const int* Ks = (const int*)d_in[4];
  const int* Kt = (const int*)d_in[5];
  int* out = (int*)d_out;
  char* ws = (char*)d_ws;

  // ws layout: bandidx (21 MB, first 4 MiB aliased by hist1 — hist dead before gather),
  // bits (2 MiB), small scalars + LUTs.  Total ~23.2 MB.
  uint32_t* bandidx = (uint32_t*)ws;                       // 128*40960*4 = 20,971,520
  uint32_t* hist1   = (uint32_t*)ws;                       // 4 MiB alias
  uint8_t*  bits    = (uint8_t*)(ws + 20971520);           // 2 MiB
  char*     sm      = ws + 23068672;
  uint32_t* bandcnt = (uint32_t*)(sm + 0);                 // 512
  uint32_t* cntabv  = (uint32_t*)(sm + 512);               // 512
  uint32_t* lo1     = (uint32_t*)(sm + 1024);              // 512
  float*    c1src   = (float*)(sm + 1536);                 // 32 KiB
  float*    c1tgt   = (float*)(sm + 1536 + 32768);         // 32 KiB
  float*    cpref   = (float*)(sm + 1536 + 65536);         // 512 B (65 used)

  lut_kernel<<<B_, T_, 0, stream>>>(Uts, Utt, c1src, c1tgt, cpref);

  // ---- SRC mask -> out[0 .. B*N) ----
  hipMemsetAsync(hist1, 0, (size_t)BINS1 * B_ * 4, stream);
  hipMemsetAsync(sm, 0, 1024, stream);                     // bandcnt + cntabove
  histA<false><<<HGRID, 256, 0, stream>>>(U0s, c1src, cpref, nullptr, hist1);
  pickbin1<<<B_, 256, 0, stream>>>(hist1, Ks, lo1);
  maskD<false><<<FULLG, 256, 0, stream>>>(U0s, c1src, cpref, nullptr, lo1,
                                          out, bits, bandcnt, cntabv, bandidx);
  resolveE<false><<<B_, 256, 0, stream>>>(U0s, c1src, cpref, nullptr, Ks, lo1,
                                          bandcnt, cntabv, bandidx, out, bits);

  // ---- TGT mask (conditioned on src bits) -> out[B*N .. 2*B*N) ----
  int* out2 = out + (size_t)B_ * N_;
  hipMemsetAsync(hist1, 0, (size_t)BINS1 * B_ * 4, stream);
  hipMemsetAsync(sm, 0, 1024, stream);
  histA<true><<<HGRID, 256, 0, stream>>>(U0t, c1tgt, cpref, bits, hist1);
  pickbin1<<<B_, 256, 0, stream>>>(hist1, Kt, lo1);
  maskD<true><<<FULLG, 256, 0, stream>>>(U0t, c1tgt, cpref, bits, lo1,
                                         out2, nullptr, bandcnt, cntabv, bandidx);
  resolveE<true><<<B_, 256, 0, stream>>>(U0t, c1tgt, cpref, bits, Kt, lo1,
                                         bandcnt, cntabv, bandidx, out2, nullptr);
}

// Round 4
// 539.792 us; speedup vs baseline: 1.1445x; 1.1445x over previous
//
#include <hip/hip_runtime.h>
#include <stdint.h>

#define B_     128
#define T_     64
#define HW_    2048
#define N_     131072
#define NB_    16384      /* N_/8 bytes of src bitmask per row */
#define BINS1  8192
#define SHIFT1 19
#define MARGIN 512u       /* band margin in key-ulps (>= ERR) */
#define CAP    40960      /* band candidates per row (tgt ~27.5k expected) */
#define SEG    4          /* histA partial-hist segments per row */
#define NB2    9216       /* resolveE sub-bins: (2^19+1024)/64 = 8208, padded to 1024*9 */
#define NMWIN  16         /* W half-window in sub-bins: 16*64 = 1024 ulps = M */
#define WCAP   2048
#define HGRID  (B_ * SEG)
#define FULLG  (B_ * 64)  /* maskD: 64 t-slots/row, 2048 elems per block */

// ---------- helpers ----------

__device__ __forceinline__ uint32_t fkey(float p) {
  uint32_t u = __float_as_uint(p);
  return u ^ ((u & 0x80000000u) ? 0xFFFFFFFFu : 0x80000000u);
}

// fast natural log: hardware v_log_f32 (log2) * ln2; deterministic.
__device__ __forceinline__ float fastln(float x) {
  #pragma clang fp contract(off)
  float l2 = __log2f(x);
  return l2 * 0.6931471805599453f;
}

// exact: correctly-rounded f32 natural log via double (matches numpy f32 log — R2/R3 verified)
__device__ __forceinline__ float exactln(float x) {
  return (float)log((double)x);
}

// ---------- LUT: per (b,t) constants, exact f32 semantics ----------
__global__ void lut_kernel(const float* __restrict__ Uts, const float* __restrict__ Utt,
                           float* c1src, float* c1tgt, float* cpref) {
  #pragma clang fp contract(off)
  int b = blockIdx.x, t = threadIdx.x;
  c1src[b * T_ + t] = exactln(Uts[b * T_ + t]) * 0.5f;
  c1tgt[b * T_ + t] = exactln(Utt[b * T_ + t]) * 0.5f;
  if (b == 0) {
    const double st = (0.001 - 1.0) / 63.0;   // numpy linspace step (f64)
    double a = (double)t * st;
    double y = a + 1.0;
    if (t == 63) y = 0.001;                   // numpy endpoint fixup
    float L = (float)y;
    float ex = (float)(1.0 / 3.0);
    float pf = (float)pow((double)L, (double)ex);
    if (pf < 1e-9f) pf = 1e-9f;
    cpref[t] = exactln(pf);
    if (t == 0) cpref[64] = exactln(1e-9f);
  }
}

// ---------- A: partial histograms of fast keys, 32768 elems/block, non-atomic flush ----------
template <bool TGT>
__global__ __launch_bounds__(256) void histA(const float* __restrict__ U0,
                                             const float* __restrict__ c1lut,
                                             const float* __restrict__ cpref,
                                             const uint8_t* __restrict__ bits,
                                             uint32_t* __restrict__ hist1) {
  #pragma clang fp contract(off)
  __shared__ uint32_t lh[BINS1];
  for (int i = threadIdx.x; i < BINS1; i += 256) lh[i] = 0;
  __syncthreads();
  int row = blockIdx.x >> 2, seg = blockIdx.x & 3;
  const float* rowp = U0 + (size_t)row * N_;
  float lc9 = cpref[64];
  // 16 t-slots per segment; process 2 slots per iteration for MLP
  for (int s = 0; s < 16; s += 2) {
    int slot0 = seg * 16 + s;
    float u[16];
    uint8_t byteg[2];
    #pragma unroll
    for (int g = 0; g < 2; g++) {
      int n0 = (slot0 + g) * HW_ + threadIdx.x * 8;
      const float4* p = (const float4*)(rowp + n0);
      float4 va = p[0], vb = p[1];
      u[g*8+0]=va.x; u[g*8+1]=va.y; u[g*8+2]=va.z; u[g*8+3]=va.w;
      u[g*8+4]=vb.x; u[g*8+5]=vb.y; u[g*8+6]=vb.z; u[g*8+7]=vb.w;
      byteg[g] = TGT ? bits[(size_t)row * NB_ + (n0 >> 3)] : (uint8_t)0;
    }
    #pragma unroll
    for (int g = 0; g < 2; g++) {
      int slot = slot0 + g;
      float c1 = c1lut[row * T_ + slot];
      float c2s = cpref[slot];
      #pragma unroll
      for (int j = 0; j < 8; j++) {
        float c2 = TGT ? ((((byteg[g] >> j) & 1) != 0) ? lc9 : 0.0f) : c2s;
        float P = (fastln(u[g*8+j]) + c1) + c2;
        atomicAdd(&lh[fkey(P) >> SHIFT1], 1u);
      }
    }
  }
  __syncthreads();
  // non-atomic flush: full overwrite of this block's [row][seg] slice
  uint32_t* gh = hist1 + ((size_t)(row * SEG + seg)) * BINS1;
  for (int i = threadIdx.x * 4; i < BINS1; i += 1024) {
    uint4 v = *(uint4*)&lh[i];
    *(uint4*)&gh[i] = v;
  }
}

// ---------- pick bin1 (descending rank K) from summed partials; zero per-row counters ----------
__global__ __launch_bounds__(256) void pickbin1(const uint32_t* __restrict__ hist1,
                                                const int* __restrict__ pK,
                                                uint32_t* lo1,
                                                uint32_t* bandcnt, uint32_t* cntabove) {
  __shared__ uint32_t sum[BINS1];
  __shared__ uint32_t sh[256];
  int row = blockIdx.x;
  const uint32_t* h = hist1 + (size_t)row * SEG * BINS1;
  for (int i = threadIdx.x; i < BINS1; i += 256) {
    uint32_t s = 0;
    #pragma unroll
    for (int g = 0; g < SEG; g++) s += h[g * BINS1 + i];
    sum[i] = s;
  }
  __syncthreads();
  const int CH = BINS1 / 256;
  {
    uint32_t s = 0;
    int c0 = threadIdx.x * CH;
    for (int i = 0; i < CH; i++) s += sum[c0 + i];
    sh[threadIdx.x] = s;
  }
  __syncthreads();
  if (threadIdx.x == 0) {
    uint32_t K = (uint32_t)*pK;
    uint32_t cum = 0, bin = 0;
    for (int c = 255; c >= 0; c--) {
      if (cum + sh[c] >= K) {
        uint32_t cc = cum;
        for (int b0 = c * CH + CH - 1; b0 >= c * CH; b0--) {
          uint32_t hv = sum[b0];
          if (cc + hv >= K) { bin = (uint32_t)b0; break; }
          cc += hv;
        }
        break;
      }
      cum += sh[c];
    }
    lo1[row] = bin << SHIFT1;
    bandcnt[row] = 0;
    cntabove[row] = 0;
  }
}

// ---------- D: write mask (int32 0/1), gather band (idx,fastkey), count above ----------
template <bool TGT>
__global__ __launch_bounds__(256) void maskD(const float* __restrict__ U0,
                                             const float* __restrict__ c1lut,
                                             const float* __restrict__ cpref,
                                             const uint8_t* __restrict__ bits_in,
                                             const uint32_t* __restrict__ lo1v,
                                             int* __restrict__ out,
                                             uint8_t* __restrict__ bits_out,
                                             uint32_t* __restrict__ bandcnt,
                                             uint32_t* __restrict__ cntabove,
                                             uint2* __restrict__ bandpair) {
  #pragma clang fp contract(off)
  __shared__ uint32_t lbase, labove, gbase;
  if (threadIdx.x == 0) { lbase = 0; labove = 0; }
  __syncthreads();
  int row = blockIdx.x >> 6, slot = blockIdx.x & 63;
  int n0 = slot * HW_ + threadIdx.x * 8;
  uint32_t lo1 = lo1v[row];
  uint32_t blo = (lo1 >= MARGIN) ? lo1 - MARGIN : 0u;
  uint32_t bhi = lo1 + ((1u << SHIFT1) - 1u);
  uint32_t bhi2 = bhi + MARGIN;
  bhi = (bhi2 < bhi) ? 0xFFFFFFFFu : bhi2;   // saturate
  const float4* p = (const float4*)(U0 + (size_t)row * N_ + n0);
  float4 va = p[0], vb = p[1];
  float u[8] = {va.x, va.y, va.z, va.w, vb.x, vb.y, vb.z, vb.w};
  float c1 = c1lut[row * T_ + slot];
  float c2s = cpref[slot];
  float lc9 = cpref[64];
  uint8_t byte = TGT ? bits_in[(size_t)row * NB_ + (n0 >> 3)] : (uint8_t)0;
  int ov[8];
  uint32_t kk[8];
  uint32_t bandmask = 0, abovemask = 0;
  #pragma unroll
  for (int j = 0; j < 8; j++) {
    float c2 = TGT ? ((((byte >> j) & 1) != 0) ? lc9 : 0.0f) : c2s;
    float P = (fastln(u[j]) + c1) + c2;
    uint32_t k = fkey(P);
    kk[j] = k;
    if (k > bhi) { ov[j] = 1; abovemask |= (1u << j); }
    else { ov[j] = 0; if (k >= blo) bandmask |= (1u << j); }
  }
  int4 o0 = {ov[0], ov[1], ov[2], ov[3]};
  int4 o1 = {ov[4], ov[5], ov[6], ov[7]};
  int4* q = (int4*)(out + (size_t)row * N_ + n0);
  q[0] = o0; q[1] = o1;
  if (!TGT) bits_out[(size_t)row * NB_ + (n0 >> 3)] = (uint8_t)abovemask;
  int bp = __popc(bandmask), ap = __popc(abovemask);
  uint32_t mybase = 0;
  if (bp) mybase = atomicAdd(&lbase, (uint32_t)bp);
  if (ap) atomicAdd(&labove, (uint32_t)ap);
  __syncthreads();
  if (threadIdx.x == 0) {
    gbase = lbase ? atomicAdd(&bandcnt[row], lbase) : 0u;
    if (labove) atomicAdd(&cntabove[row], labove);
  }
  __syncthreads();
  if (bp) {
    uint32_t base = gbase + mybase;
    uint2* br = bandpair + (size_t)row * CAP;
    #pragma unroll
    for (int j = 0; j < 8; j++)
      if ((bandmask >> j) & 1u) {
        uint32_t pos = base + (uint32_t)__popc(bandmask & ((1u << j) - 1u));
        if (pos < CAP) { uint2 e; e.x = (uint32_t)(n0 + j); e.y = kk[j]; br[pos] = e; }
      }
  }
}

// ---------- E: streaming fast-key refine + tiny exact resolve ----------
template <bool TGT>
__global__ __launch_bounds__(1024) void resolveE(const float* __restrict__ U0,
                                                 const float* __restrict__ c1lut,
                                                 const float* __restrict__ cpref,
                                                 const uint8_t* __restrict__ bits_in,
                                                 const int* __restrict__ pK,
                                                 const uint32_t* __restrict__ lo1v,
                                                 const uint32_t* __restrict__ bandcnt,
                                                 const uint32_t* __restrict__ cntabove,
                                                 const uint2* __restrict__ bandpair,
                                                 int* __restrict__ out,
                                                 uint8_t* __restrict__ bits_out) {
  #pragma clang fp contract(off)
  __shared__ uint32_t subh[NB2];
  __shared__ uint32_t sh2[1024];
  __shared__ uint32_t wk[WCAP];
  __shared__ uint32_t wi[WCAP];
  __shared__ uint32_t s_sbin, s_A, s_nw;
  int row = blockIdx.x;
  for (int i = threadIdx.x; i < NB2; i += 1024) subh[i] = 0;
  if (threadIdx.x == 0) s_nw = 0;
  __syncthreads();
  uint32_t cnt = bandcnt[row]; if (cnt > CAP) cnt = CAP;
  uint32_t K = (uint32_t)*pK;
  uint32_t R = K - cntabove[row];           // band elements to select; >=1 by construction
  uint32_t lo1 = lo1v[row];
  uint32_t blo = (lo1 >= MARGIN) ? lo1 - MARGIN : 0u;   // same clamp as maskD
  const uint2* bp = bandpair + (size_t)row * CAP;

  // pass 1: fast-key sub-histogram (64-ulp bins), sequential stream
  for (uint32_t i = threadIdx.x; i < cnt; i += 1024) {
    uint32_t k = bp[i].y;
    uint32_t off = k - blo;
    uint32_t bin = off >> 6;
    if (bin >= NB2) bin = NB2 - 1;
    atomicAdd(&subh[bin], 1u);
  }
  __syncthreads();
  // pick sub-bin (descending rank R); compute A = count(fk > subhi + M)
  const int CH2 = NB2 / 1024;   // 9
  {
    uint32_t s = 0;
    int c0 = threadIdx.x * CH2;
    #pragma unroll
    for (int i = 0; i < CH2; i++) s += subh[c0 + i];
    sh2[threadIdx.x] = s;
  }
  __syncthreads();
  if (threadIdx.x == 0) {
    uint32_t cum = 0, chi = 0; int sbin = 0;
    for (int c = 1023; c >= 0; c--) {
      if (cum + sh2[c] >= R) {
        uint32_t cc = cum;
        for (int b0 = c * CH2 + CH2 - 1; b0 >= c * CH2; b0--) {
          uint32_t hv = subh[b0];
          if (cc + hv >= R) { sbin = b0; chi = cc; break; }
          cc += hv;
        }
        break;
      }
      cum += sh2[c];
    }
    // chi = count(fk in bins > sbin). A = chi - count(bins sbin+1 .. sbin+NMWIN)
    uint32_t sm = 0;
    for (int k2 = 1; k2 <= NMWIN; k2++) {
      int b2 = sbin + k2;
      if (b2 < NB2) sm += subh[b2];
    }
    s_sbin = (uint32_t)sbin;
    s_A = chi - sm;
  }
  __syncthreads();
  int sbin = (int)s_sbin;
  uint32_t A = s_A;
  uint32_t R2 = R - A;                      // to select from W window; >=1
  int* orow = out + (size_t)row * N_;

  // pass 2: classify band by sub-bin; definite-selects written, W collected
  for (uint32_t i = threadIdx.x; i < cnt; i += 1024) {
    uint2 e = bp[i];
    uint32_t off = e.y - blo;
    uint32_t bin = off >> 6;
    if (bin >= NB2) bin = NB2 - 1;
    if ((int)bin > sbin + NMWIN) {
      orow[e.x] = 1;
      if (!TGT) atomicOr((uint32_t*)(bits_out + (size_t)row * NB_) + (e.x >> 5), 1u << (e.x & 31));
    } else if ((int)bin >= sbin - NMWIN) {
      uint32_t ppos = atomicAdd(&s_nw, 1u);
      if (ppos < WCAP) wi[ppos] = e.x;
    }
  }
  __syncthreads();
  uint32_t nw = s_nw; if (nw > WCAP) nw = WCAP;
  // pass 3a: exact keys for W (few hundred f64 logs + gathers)
  const uint8_t* rb = bits_in + (size_t)row * NB_;
  const float* rowp = U0 + (size_t)row * N_;
  float lc9 = cpref[64];
  for (uint32_t i = threadIdx.x; i < nw; i += 1024) {
    uint32_t idx = wi[i];
    uint32_t t = idx >> 11;
    float c2 = TGT ? ((((rb[idx >> 3] >> (idx & 7)) & 1) != 0) ? lc9 : 0.0f) : cpref[t];
    float P = (exactln(rowp[idx]) + c1lut[row * T_ + t]) + c2;
    wk[i] = fkey(P);
  }
  __syncthreads();
  // pass 3b: stable pairwise rank in W, select top R2
  for (uint32_t i = threadIdx.x; i < nw; i += 1024) {
    uint32_t k = wk[i], id = wi[i], r = 0;
    for (uint32_t j = 0; j < nw; j++) {
      uint32_t kj = wk[j];
      r += (uint32_t)((kj > k) || (kj == k && wi[j] < id));
    }
    if (r < R2) {
      orow[id] = 1;
      if (!TGT) atomicOr((uint32_t*)(bits_out + (size_t)row * NB_) + (id >> 5), 1u << (id & 31));
    }
  }
}

// ---------- launch ----------
extern "C" void kernel_launch(void* const* d_in, const int* in_sizes, int n_in,
                              void* d_out, int out_size, void* d_ws, size_t ws_size,
                              hipStream_t stream) {
  const float* U0s = (const float*)d_in[0];
  const float* Uts = (const float*)d_in[1];
  const float* U0t = (const float*)d_in[2];
  const float* Utt = (const float*)d_in[3];
  const int* Ks = (const int*)d_in[4];
  const int* Kt = (const int*)d_in[5];
  int* out = (int*)d_out;
  char* ws = (char*)d_ws;

  // ws layout: bandpair 41.9 MB (first 16.8 MB aliased by hist1 — hist dead before
  // maskD writes bandpair), bits 2 MiB, small LUTs. Total ~44.1 MB.
  uint2*    bandpair = (uint2*)ws;                         // 128*40960*8 = 41,943,040
  uint32_t* hist1    = (uint32_t*)ws;                      // SEG*128*8192*4 = 16,777,216 alias
  uint8_t*  bits     = (uint8_t*)(ws + 41943040);          // 2 MiB
  char*     sm       = ws + 44040192;
  uint32_t* bandcnt  = (uint32_t*)(sm + 0);                // 512
  uint32_t* cntabv   = (uint32_t*)(sm + 512);              // 512
  uint32_t* lo1      = (uint32_t*)(sm + 1024);             // 512
  float*    c1src    = (float*)(sm + 1536);                // 32 KiB
  float*    c1tgt    = (float*)(sm + 1536 + 32768);        // 32 KiB
  float*    cpref    = (float*)(sm + 1536 + 65536);        // 512 B (65 used)

  lut_kernel<<<B_, T_, 0, stream>>>(Uts, Utt, c1src, c1tgt, cpref);

  // ---- SRC mask -> out[0 .. B*N) ----
  histA<false><<<HGRID, 256, 0, stream>>>(U0s, c1src, cpref, nullptr, hist1);
  pickbin1<<<B_, 256, 0, stream>>>(hist1, Ks, lo1, bandcnt, cntabv);
  maskD<false><<<FULLG, 256, 0, stream>>>(U0s, c1src, cpref, nullptr, lo1,
                                          out, bits, bandcnt, cntabv, bandpair);
  resolveE<false><<<B_, 1024, 0, stream>>>(U0s, c1src, cpref, nullptr, Ks, lo1,
                                           bandcnt, cntabv, bandpair, out, bits);

  // ---- TGT mask (conditioned on src bits) -> out[B*N .. 2*B*N) ----
  int* out2 = out + (size_t)B_ * N_;
  histA<true><<<HGRID, 256, 0, stream>>>(U0t, c1tgt, cpref, bits, hist1);
  pickbin1<<<B_, 256, 0, stream>>>(hist1, Kt, lo1, bandcnt, cntabv);
  maskD<true><<<FULLG, 256, 0, stream>>>(U0t, c1tgt, cpref, bits, lo1,
                                         out2, nullptr, bandcnt, cntabv, bandpair);
  resolveE<true><<<B_, 1024, 0, stream>>>(U0t, c1tgt, cpref, bits, Kt, lo1,
                                          bandcnt, cntabv, bandpair, out2, nullptr);
}